// Round 1
// baseline (1956.864 us; speedup 1.0000x reference)
//
#include <hip/hip_runtime.h>
#include <hip/hip_bf16.h>
#include <math.h>

#define BB 8
#define CC 1024
#define TT 1024
#define HH 16
#define DD 64

// ---------------------------------------------------------------------------
// Kernel 1: fused QKV conv1x1 + bias + RoPE + head-split
// out[b,h,t,d] layout [B,H,T,D]. Tile: M=64 (one head's d), N=64 (t), K=16.
// Thread (tx,ty) of (16,16): rows d = tx+16i, cols t = ty+16j.
// RoPE pairs (d, d+16) live in (acc[0][j], acc[1][j]) of the same thread.
// ---------------------------------------------------------------------------
template<typename ST>
__global__ __launch_bounds__(256) void qkv_rope_kernel(
    const float* __restrict__ x, const float* __restrict__ ctx,
    const float* __restrict__ Wq, const float* __restrict__ bq,
    const float* __restrict__ Wk, const float* __restrict__ bk,
    const float* __restrict__ Wv, const float* __restrict__ bv,
    ST* __restrict__ qo, ST* __restrict__ ko, ST* __restrict__ vo)
{
    __shared__ float sW[16*66];   // [kc][o] transposed, stride 66 breaks conflicts
    __shared__ float sIn[16*64];  // [kc][t]

    const int tx = threadIdx.x, ty = threadIdx.y;
    const int tid = ty*16 + tx;
    const int tTile = blockIdx.x, head = blockIdx.y;
    const int b = blockIdx.z / 3, w = blockIdx.z % 3;

    const float* in   = (w==0) ? x  : ctx;
    const float* W    = (w==0) ? Wq : (w==1) ? Wk : Wv;
    const float* bias = (w==0) ? bq : (w==1) ? bk : bv;
    ST* outp          = (w==0) ? qo : (w==1) ? ko : vo;

    const int oBase = head*64, tBase = tTile*64;
    const float* inB = in + (size_t)b*CC*TT;

    const int wr = tid>>2, wc = (tid&3)*4;   // W tile: 64 rows x 16 cols
    const int ir = tid>>4, ic = (tid&15)*4;  // In tile: 16 rows x 64 cols

    float acc[4][4] = {};

    for (int c0 = 0; c0 < CC; c0 += 16) {
        float4 w4 = *(const float4*)(W + (size_t)(oBase+wr)*CC + c0 + wc);
        sW[(wc+0)*66 + wr] = w4.x;
        sW[(wc+1)*66 + wr] = w4.y;
        sW[(wc+2)*66 + wr] = w4.z;
        sW[(wc+3)*66 + wr] = w4.w;
        *(float4*)(sIn + ir*64 + ic) =
            *(const float4*)(inB + (size_t)(c0+ir)*TT + tBase + ic);
        __syncthreads();
        #pragma unroll
        for (int kc = 0; kc < 16; kc++) {
            float a[4], bb[4];
            #pragma unroll
            for (int i=0;i<4;i++) a[i] = sW[kc*66 + tx + 16*i];
            #pragma unroll
            for (int j=0;j<4;j++) bb[j] = sIn[kc*64 + ty + 16*j];
            #pragma unroll
            for (int i=0;i<4;i++)
                #pragma unroll
                for (int j=0;j<4;j++)
                    acc[i][j] = fmaf(a[i], bb[j], acc[i][j]);
        }
        __syncthreads();
    }

    #pragma unroll
    for (int i=0;i<4;i++) {
        float bi = bias[oBase + tx + 16*i];
        #pragma unroll
        for (int j=0;j<4;j++) acc[i][j] += bi;
    }

    if (w < 2) {  // RoPE on q and k only. d = tx (i=0) pairs with d = tx+16 (i=1)
        float theta = powf(10000.0f, -(float)tx * (1.0f/16.0f));
        #pragma unroll
        for (int j=0;j<4;j++) {
            float tpos = (float)(tBase + ty + 16*j);
            float sa, ca;
            sincosf(tpos*theta, &sa, &ca);
            float x0 = acc[0][j], x1 = acc[1][j];
            acc[0][j] = x0*ca - x1*sa;   // out[d]    = x[d]cos - x[d+16]sin
            acc[1][j] = x1*ca + x0*sa;   // out[d+16] = x[d+16]cos + x[d]sin
        }
    }

    #pragma unroll
    for (int j=0;j<4;j++) {
        int t = tBase + ty + 16*j;
        ST* dst = outp + (((size_t)b*HH + head)*TT + t)*DD;
        #pragma unroll
        for (int i=0;i<4;i++) dst[tx + 16*i] = (ST)acc[i][j];
    }
}

// ---------------------------------------------------------------------------
// Kernel 2: flash-style attention per (b,h,64-row Q tile).
// scores = qk/8 - log1p(|k-q|), mask==0 -> -1e4, online softmax, PV.
// Thread (tx,ty): S rows q=ty+16i, cols k=tx+16j; O rows q=ty+16i, cols d=tx+16j.
// ---------------------------------------------------------------------------
template<typename ST>
__global__ __launch_bounds__(256) void attn_kernel(
    const ST* __restrict__ q, const ST* __restrict__ k, const ST* __restrict__ v,
    const int* __restrict__ mask, ST* __restrict__ att)
{
    __shared__ float sQ[64*68];   // [q][d], stride 68 (bank-safe, 16B aligned)
    __shared__ float sKP[64*68];  // K tile [k][d]; reused as P tile [q][k]
    __shared__ float sV[64*64];   // [k][d]

    const int tx = threadIdx.x, ty = threadIdx.y;
    const int tid = ty*16 + tx;
    const int qTile = blockIdx.x;
    const int bh = blockIdx.y;
    const int b = bh >> 4;

    const int lr = tid>>4;        // 0..15
    const int lc = (tid&15)*4;    // 0..60

    const ST* qB = q + ((size_t)bh*TT + qTile*64)*DD;
    #pragma unroll
    for (int u=0;u<4;u++) {
        int r = lr + u*16;
        const ST* src = qB + r*DD + lc;
        float4 f;
        f.x = 0.125f*(float)src[0]; f.y = 0.125f*(float)src[1];
        f.z = 0.125f*(float)src[2]; f.w = 0.125f*(float)src[3];
        *(float4*)(sQ + r*68 + lc) = f;
    }

    float m_i[4], l_i[4], accO[4][4];
    #pragma unroll
    for (int i=0;i<4;i++) {
        m_i[i] = -1e30f; l_i[i] = 0.f;
        #pragma unroll
        for (int j=0;j<4;j++) accO[i][j] = 0.f;
    }

    const int* maskB = mask + b*TT;
    const ST* kB = k + (size_t)bh*TT*DD;
    const ST* vB = v + (size_t)bh*TT*DD;

    for (int kt = 0; kt < 16; kt++) {
        __syncthreads();  // prior iter done reading sKP/sV; sQ visible at kt=0
        #pragma unroll
        for (int u=0;u<4;u++) {
            int r = lr + u*16;
            const ST* ks = kB + ((size_t)(kt*64 + r))*DD + lc;
            float4 f;
            f.x=(float)ks[0]; f.y=(float)ks[1]; f.z=(float)ks[2]; f.w=(float)ks[3];
            *(float4*)(sKP + r*68 + lc) = f;
            const ST* vs = vB + ((size_t)(kt*64 + r))*DD + lc;
            float4 g;
            g.x=(float)vs[0]; g.y=(float)vs[1]; g.z=(float)vs[2]; g.w=(float)vs[3];
            *(float4*)(sV + r*64 + lc) = g;
        }
        __syncthreads();

        // S = (Q/8) . K^T
        float s[4][4] = {};
        for (int d=0; d<64; d++) {
            float aq[4], bk4[4];
            #pragma unroll
            for (int i=0;i<4;i++) aq[i]  = sQ [(ty+16*i)*68 + d];
            #pragma unroll
            for (int j=0;j<4;j++) bk4[j] = sKP[(tx+16*j)*68 + d];
            #pragma unroll
            for (int i=0;i<4;i++)
                #pragma unroll
                for (int j=0;j<4;j++)
                    s[i][j] = fmaf(aq[i], bk4[j], s[i][j]);
        }

        // proximal bias + mask
        #pragma unroll
        for (int j=0;j<4;j++) {
            int kpos = kt*64 + tx + 16*j;
            int mk = maskB[kpos];
            #pragma unroll
            for (int i=0;i<4;i++) {
                int qpos = qTile*64 + ty + 16*i;
                float sv_ = s[i][j] - log1pf(fabsf((float)(kpos - qpos)));
                s[i][j] = (mk == 0) ? -10000.0f : sv_;
            }
        }

        // online softmax (row reduction across the 16 tx lanes of each wave)
        float p[4][4];
        #pragma unroll
        for (int i=0;i<4;i++) {
            float mt = fmaxf(fmaxf(s[i][0],s[i][1]), fmaxf(s[i][2],s[i][3]));
            #pragma unroll
            for (int off=1; off<16; off<<=1)
                mt = fmaxf(mt, __shfl_xor(mt, off, 64));
            float mn = fmaxf(m_i[i], mt);
            float alpha = __expf(m_i[i] - mn);
            m_i[i] = mn;
            float rs = 0.f;
            #pragma unroll
            for (int j=0;j<4;j++) { p[i][j] = __expf(s[i][j] - mn); rs += p[i][j]; }
            #pragma unroll
            for (int off=1; off<16; off<<=1)
                rs += __shfl_xor(rs, off, 64);
            l_i[i] = l_i[i]*alpha + rs;
            #pragma unroll
            for (int j=0;j<4;j++) accO[i][j] *= alpha;
        }

        __syncthreads();  // all done reading sKP as K
        #pragma unroll
        for (int i=0;i<4;i++)
            #pragma unroll
            for (int j=0;j<4;j++)
                sKP[(ty+16*i)*68 + tx+16*j] = p[i][j];
        __syncthreads();

        // O += P . V
        for (int kk=0; kk<64; kk++) {
            float pv[4], vv[4];
            #pragma unroll
            for (int i=0;i<4;i++) pv[i] = sKP[(ty+16*i)*68 + kk];
            #pragma unroll
            for (int j=0;j<4;j++) vv[j] = sV[kk*64 + tx+16*j];
            #pragma unroll
            for (int i=0;i<4;i++)
                #pragma unroll
                for (int j=0;j<4;j++)
                    accO[i][j] = fmaf(pv[i], vv[j], accO[i][j]);
        }
    }

    #pragma unroll
    for (int i=0;i<4;i++) {
        float inv = 1.0f / l_i[i];
        int qpos = qTile*64 + ty + 16*i;
        ST* dst = att + ((size_t)bh*TT + qpos)*DD;
        #pragma unroll
        for (int j=0;j<4;j++) dst[tx + 16*j] = (ST)(accO[i][j]*inv);
    }
}

// ---------------------------------------------------------------------------
// Kernel 3: output conv1x1. in[c,t] = att[b, c>>6, t, c&63]; out[b,o,t] fp32.
// Thread (tx,ty): rows o = ty+16i, cols t = tx+16j (coalesced stores).
// ---------------------------------------------------------------------------
template<typename ST>
__global__ __launch_bounds__(256) void out_gemm_kernel(
    const ST* __restrict__ att, const float* __restrict__ Wo,
    const float* __restrict__ bo, float* __restrict__ out)
{
    __shared__ float sW[16*66];
    __shared__ float sIn[16*68];

    const int tx = threadIdx.x, ty = threadIdx.y;
    const int tid = ty*16 + tx;
    const int tTile = blockIdx.x, oTile = blockIdx.y, b = blockIdx.z;
    const int oBase = oTile*64, tBase = tTile*64;

    const int wr = tid>>2, wc = (tid&3)*4;
    const int ar = tid & 15;        // c-row within K tile
    const int ac = (tid>>4)*4;      // t-col start

    float acc[4][4] = {};

    for (int c0 = 0; c0 < CC; c0 += 16) {
        float4 w4 = *(const float4*)(Wo + (size_t)(oBase+wr)*CC + c0 + wc);
        sW[(wc+0)*66 + wr] = w4.x;
        sW[(wc+1)*66 + wr] = w4.y;
        sW[(wc+2)*66 + wr] = w4.z;
        sW[(wc+3)*66 + wr] = w4.w;
        int c = c0 + ar;
        const ST* aB = att + (((size_t)b*HH + (c>>6))*TT + tBase + ac)*DD + (c&63);
        #pragma unroll
        for (int u=0;u<4;u++)
            sIn[ar*68 + ac + u] = (float)aB[(size_t)u*DD];
        __syncthreads();
        #pragma unroll
        for (int kc=0;kc<16;kc++) {
            float a[4], bb[4];
            #pragma unroll
            for (int i=0;i<4;i++) a[i] = sW[kc*66 + ty + 16*i];
            #pragma unroll
            for (int j=0;j<4;j++) bb[j] = sIn[kc*68 + tx + 16*j];
            #pragma unroll
            for (int i=0;i<4;i++)
                #pragma unroll
                for (int j=0;j<4;j++)
                    acc[i][j] = fmaf(a[i], bb[j], acc[i][j]);
        }
        __syncthreads();
    }

    #pragma unroll
    for (int i=0;i<4;i++) {
        int o = oBase + ty + 16*i;
        float bi = bo[o];
        float* dst = out + ((size_t)b*CC + o)*TT + tBase;
        #pragma unroll
        for (int j=0;j<4;j++) dst[tx + 16*j] = acc[i][j] + bi;
    }
}

// ---------------------------------------------------------------------------
template<typename ST>
static void launch_all(const float* x, const float* ctx, const int* mask,
                       const float* Wq, const float* bq, const float* Wk, const float* bk,
                       const float* Wv, const float* bv, const float* Wo, const float* bo,
                       float* out, void* ws, hipStream_t stream)
{
    const size_t nq = (size_t)BB*HH*TT*DD;
    ST* q   = (ST*)ws;
    ST* k   = q + nq;
    ST* v   = k + nq;
    ST* att = v + nq;
    dim3 blk(16,16);
    qkv_rope_kernel<ST><<<dim3(16,16,BB*3), blk, 0, stream>>>(
        x, ctx, Wq, bq, Wk, bk, Wv, bv, q, k, v);
    attn_kernel<ST><<<dim3(TT/64, BB*HH), blk, 0, stream>>>(q, k, v, mask, att);
    out_gemm_kernel<ST><<<dim3(16,16,BB), blk, 0, stream>>>(att, Wo, bo, out);
}

extern "C" void kernel_launch(void* const* d_in, const int* in_sizes, int n_in,
                              void* d_out, int out_size, void* d_ws, size_t ws_size,
                              hipStream_t stream)
{
    const float* x   = (const float*)d_in[0];
    const float* ctx = (const float*)d_in[1];
    const int* mask  = (const int*)d_in[2];
    const float* Wq  = (const float*)d_in[3];
    const float* bq  = (const float*)d_in[4];
    const float* Wk  = (const float*)d_in[5];
    const float* bk  = (const float*)d_in[6];
    const float* Wv  = (const float*)d_in[7];
    const float* bv  = (const float*)d_in[8];
    const float* Wo  = (const float*)d_in[9];
    const float* bo  = (const float*)d_in[10];
    float* out = (float*)d_out;

    const size_t nq = (size_t)BB*HH*TT*DD;
    if (ws_size >= 4*nq*sizeof(float)) {
        launch_all<float>(x, ctx, mask, Wq, bq, Wk, bk, Wv, bv, Wo, bo, out, d_ws, stream);
    } else {
        // bf16 intermediate storage fallback (64 MB): fp32 compute, bf16 staging
        launch_all<__hip_bfloat16>(x, ctx, mask, Wq, bq, Wk, bk, Wv, bv, Wo, bo, out, d_ws, stream);
    }
}

// Round 2
// 748.376 us; speedup vs baseline: 2.6148x; 2.6148x over previous
//
#include <hip/hip_runtime.h>
#include <hip/hip_bf16.h>
#include <math.h>

#define BB 8
#define CC 1024
#define TT 1024
#define HH 16
#define DD 64

typedef __attribute__((ext_vector_type(8))) short short8;
typedef __attribute__((ext_vector_type(4))) short short4_;
typedef __attribute__((ext_vector_type(4))) float f32x4;

__device__ __forceinline__ unsigned short f2bf(float f) {
    unsigned u = __builtin_bit_cast(unsigned, f);
    u += 0x7fffu + ((u >> 16) & 1u);
    return (unsigned short)(u >> 16);
}

__device__ __forceinline__ f32x4 mfma16(short8 a, short8 b, f32x4 c) {
    return __builtin_amdgcn_mfma_f32_16x16x32_bf16(a, b, c, 0, 0, 0);
}

// ---------------------------------------------------------------------------
// Kernel 1: QKV conv1x1 (bf16 MFMA) + bias + RoPE + head-split.
// GEMM per (b, w in {q,k,v}): Out[o,t] = W[o,:]·In[:,t].  BM=BN=128, BK=32.
// 4 waves, wave tile 64x64 (one head's d per wave since oBase%64==0).
// q,k stored [b,h,t,d] via LDS transpose; v stored [b,h,d,t] directly.
// ---------------------------------------------------------------------------
__global__ __launch_bounds__(256) void qkv_mfma_kernel(
    const float* __restrict__ x, const float* __restrict__ ctx,
    const float* __restrict__ Wq, const float* __restrict__ bq,
    const float* __restrict__ Wk, const float* __restrict__ bk,
    const float* __restrict__ Wv, const float* __restrict__ bv,
    unsigned short* __restrict__ qo, unsigned short* __restrict__ ko,
    unsigned short* __restrict__ vo)
{
    __shared__ __align__(16) short smem[4 * 64 * 72];  // 36864 B
    short* sA = smem;              // W tile   [o 128][c 32] stride 40
    short* sB = smem + 128 * 40;   // In^T tile[t 128][c 32] stride 40

    const int tid  = threadIdx.x;
    const int lane = tid & 63;
    const int wave = tid >> 6;
    const int wm = wave >> 1, wn = wave & 1;
    const int l15 = lane & 15, lq = lane >> 4;

    const int tTile = blockIdx.x, oTile = blockIdx.y;
    const int b = blockIdx.z / 3, w = blockIdx.z % 3;
    const int oBase = oTile * 128, tBase = tTile * 128;

    const float* In   = (w == 0) ? x  : ctx;
    const float* W    = (w == 0) ? Wq : (w == 1) ? Wk : Wv;
    const float* bias = (w == 0) ? bq : (w == 1) ? bk : bv;
    const float* InB  = In + (size_t)b * CC * TT;

    const int ao = tid >> 1, ak = (tid & 1) * 16;       // A staging role
    const int bt = tid & 127, bk_ = (tid >> 7) * 16;    // B staging role
    const float* gA = W + (size_t)(oBase + ao) * CC + ak;
    const float* gB = InB + (size_t)bk_ * TT + tBase + bt;

    f32x4 acc[4][4];
    #pragma unroll
    for (int mt = 0; mt < 4; mt++)
        #pragma unroll
        for (int nt = 0; nt < 4; nt++) acc[mt][nt] = (f32x4){0.f, 0.f, 0.f, 0.f};

    for (int c0 = 0; c0 < CC; c0 += 32) {
        float fa[16], fb[16];
        #pragma unroll
        for (int i = 0; i < 4; i++) {
            float4 t4 = *(const float4*)(gA + c0 + 4 * i);
            fa[4*i+0] = t4.x; fa[4*i+1] = t4.y; fa[4*i+2] = t4.z; fa[4*i+3] = t4.w;
        }
        #pragma unroll
        for (int j = 0; j < 16; j++)
            fb[j] = gB[(size_t)(c0 + j) * TT];

        __syncthreads();
        short8 pa0, pa1, pb0, pb1;
        #pragma unroll
        for (int e = 0; e < 8; e++) {
            pa0[e] = (short)f2bf(fa[e]);   pa1[e] = (short)f2bf(fa[8 + e]);
            pb0[e] = (short)f2bf(fb[e]);   pb1[e] = (short)f2bf(fb[8 + e]);
        }
        *(short8*)(sA + ao * 40 + ak)     = pa0;
        *(short8*)(sA + ao * 40 + ak + 8) = pa1;
        *(short8*)(sB + bt * 40 + bk_)     = pb0;
        *(short8*)(sB + bt * 40 + bk_ + 8) = pb1;
        __syncthreads();

        short8 af[4], bf[4];
        #pragma unroll
        for (int mt = 0; mt < 4; mt++)
            af[mt] = *(short8*)(sA + (wm * 64 + mt * 16 + l15) * 40 + lq * 8);
        #pragma unroll
        for (int nt = 0; nt < 4; nt++)
            bf[nt] = *(short8*)(sB + (wn * 64 + nt * 16 + l15) * 40 + lq * 8);
        #pragma unroll
        for (int mt = 0; mt < 4; mt++)
            #pragma unroll
            for (int nt = 0; nt < 4; nt++)
                acc[mt][nt] = mfma16(af[mt], bf[nt], acc[mt][nt]);
    }

    // bias (C-layout: row o = mt*16 + lq*4 + r, col t = nt*16 + l15)
    #pragma unroll
    for (int mt = 0; mt < 4; mt++)
        #pragma unroll
        for (int r = 0; r < 4; r++) {
            float bi = bias[oBase + wm * 64 + mt * 16 + lq * 4 + r];
            #pragma unroll
            for (int nt = 0; nt < 4; nt++) acc[mt][nt][r] += bi;
        }

    const int h = oTile * 2 + wm;
    __syncthreads();  // everyone done with sA/sB before transpose reuse
    short* sT = smem + wave * (64 * 72);

    if (w < 2) {
        // RoPE: d = mt*16 + lq*4 + r; pair (d, d+16) = (mt=0, mt=1), d<16
        #pragma unroll
        for (int r = 0; r < 4; r++) {
            float theta = powf(10000.0f, -(float)(lq * 4 + r) * (1.0f / 16.0f));
            #pragma unroll
            for (int nt = 0; nt < 4; nt++) {
                float tpos = (float)(tBase + wn * 64 + nt * 16 + l15);
                float sa, ca;
                sincosf(tpos * theta, &sa, &ca);
                float x0 = acc[0][nt][r], x1 = acc[1][nt][r];
                acc[0][nt][r] = x0 * ca - x1 * sa;
                acc[1][nt][r] = x1 * ca + x0 * sa;
            }
        }
        // transpose to [t_local][d] (stride 72)
        #pragma unroll
        for (int nt = 0; nt < 4; nt++)
            #pragma unroll
            for (int mt = 0; mt < 4; mt++) {
                short4_ v4;
                #pragma unroll
                for (int r = 0; r < 4; r++) v4[r] = (short)f2bf(acc[mt][nt][r]);
                *(short4_*)(sT + (nt * 16 + l15) * 72 + mt * 16 + lq * 4) = v4;
            }
    } else {
        // V: buffer as [d][t_local] (stride 72), no RoPE
        #pragma unroll
        for (int mt = 0; mt < 4; mt++)
            #pragma unroll
            for (int r = 0; r < 4; r++)
                #pragma unroll
                for (int nt = 0; nt < 4; nt++)
                    sT[(mt * 16 + lq * 4 + r) * 72 + nt * 16 + l15] =
                        (short)f2bf(acc[mt][nt][r]);
    }
    __asm__ volatile("s_waitcnt lgkmcnt(0)" ::: "memory");  // within-wave LDS order

    unsigned short* dstBase;
    if (w == 0)
        dstBase = qo + ((size_t)(b * HH + h) * TT + tBase + wn * 64 + lane) * DD;
    else if (w == 1)
        dstBase = ko + ((size_t)(b * HH + h) * TT + tBase + wn * 64 + lane) * DD;
    else
        dstBase = vo + ((size_t)(b * HH + h) * DD + lane) * TT + tBase + wn * 64;
    #pragma unroll
    for (int j = 0; j < 8; j++)
        *(short8*)(dstBase + j * 8) = *(short8*)(sT + lane * 72 + j * 8);
}

// ---------------------------------------------------------------------------
// Kernel 2: flash attention, bf16 MFMA. Block = 4 waves, Q-tile 64 rows,
// wave owns 16 q-rows. K-tile 64. S & O in C-layout; P via per-wave LDS.
// ---------------------------------------------------------------------------
__global__ __launch_bounds__(256) void attn_mfma_kernel(
    const unsigned short* __restrict__ q, const unsigned short* __restrict__ k,
    const unsigned short* __restrict__ v, const int* __restrict__ mask,
    unsigned short* __restrict__ att)
{
    __shared__ __align__(16) short sQ[64 * 72];
    __shared__ __align__(16) short sK[64 * 72];
    __shared__ __align__(16) short sV[64 * 72];  // V^T tile: [d][t_k]
    __shared__ __align__(16) short sP[64 * 72];

    const int tid = threadIdx.x, lane = tid & 63, wq = tid >> 6;
    const int l15 = lane & 15, lq = lane >> 4;
    const int qTile = blockIdx.x, bh = blockIdx.y, b = bh >> 4;

    const int sr = tid >> 2, sc = (tid & 3) * 16;  // staging: row, col-chunk

    {   // stage Q once
        const unsigned short* gq = q + ((size_t)bh * TT + qTile * 64 + sr) * DD + sc;
        *(short8*)(sQ + sr * 72 + sc)     = *(const short8*)gq;
        *(short8*)(sQ + sr * 72 + sc + 8) = *(const short8*)(gq + 8);
    }

    f32x4 accO[4];
    float m_i[4], l_i[4];
    #pragma unroll
    for (int r = 0; r < 4; r++) {
        m_i[r] = -1e30f; l_i[r] = 0.f;
        accO[r] = (f32x4){0.f, 0.f, 0.f, 0.f};
    }
    #pragma unroll
    for (int nt = 0; nt < 4; nt++) accO[nt] = (f32x4){0.f, 0.f, 0.f, 0.f};

    const int* maskB = mask + b * TT;
    const unsigned short* kB = k + (size_t)bh * TT * DD;
    const unsigned short* vB = v + (size_t)bh * DD * TT;

    for (int kt = 0; kt < 16; kt++) {
        const unsigned short* gk = kB + (size_t)(kt * 64 + sr) * DD + sc;
        short8 k0 = *(const short8*)gk;
        short8 k1 = *(const short8*)(gk + 8);
        const unsigned short* gv = vB + (size_t)sr * TT + kt * 64 + sc;
        short8 v0 = *(const short8*)gv;
        short8 v1 = *(const short8*)(gv + 8);

        __syncthreads();
        *(short8*)(sK + sr * 72 + sc)     = k0;
        *(short8*)(sK + sr * 72 + sc + 8) = k1;
        *(short8*)(sV + sr * 72 + sc)     = v0;
        *(short8*)(sV + sr * 72 + sc + 8) = v1;
        __syncthreads();

        // S = Q·K^T  (m = q-row within wave block, n = t_k)
        short8 aq0 = *(short8*)(sQ + (wq * 16 + l15) * 72 + lq * 8);
        short8 aq1 = *(short8*)(sQ + (wq * 16 + l15) * 72 + 32 + lq * 8);
        f32x4 s4[4];
        #pragma unroll
        for (int nt = 0; nt < 4; nt++) {
            short8 b0 = *(short8*)(sK + (nt * 16 + l15) * 72 + lq * 8);
            short8 b1 = *(short8*)(sK + (nt * 16 + l15) * 72 + 32 + lq * 8);
            f32x4 z = (f32x4){0.f, 0.f, 0.f, 0.f};
            z = mfma16(aq0, b0, z);
            z = mfma16(aq1, b1, z);
            s4[nt] = z;
        }

        // scale + proximal bias + mask
        const int qpos0 = qTile * 64 + wq * 16 + lq * 4;
        float s[4][4];
        #pragma unroll
        for (int nt = 0; nt < 4; nt++) {
            int kpos = kt * 64 + nt * 16 + l15;
            int mk = maskB[kpos];
            #pragma unroll
            for (int r = 0; r < 4; r++) {
                float sv_ = s4[nt][r] * 0.125f
                          - log1pf(fabsf((float)(kpos - (qpos0 + r))));
                s[nt][r] = mk ? sv_ : -10000.0f;
            }
        }

        // online softmax per row r (reduce across 16 lanes of the quad-group)
        float p[4][4];
        #pragma unroll
        for (int r = 0; r < 4; r++) {
            float mt_ = fmaxf(fmaxf(s[0][r], s[1][r]), fmaxf(s[2][r], s[3][r]));
            #pragma unroll
            for (int off = 1; off < 16; off <<= 1)
                mt_ = fmaxf(mt_, __shfl_xor(mt_, off, 64));
            float mn = fmaxf(m_i[r], mt_);
            float alpha = __expf(m_i[r] - mn);
            m_i[r] = mn;
            float rs = 0.f;
            #pragma unroll
            for (int nt = 0; nt < 4; nt++) {
                p[nt][r] = __expf(s[nt][r] - mn);
                rs += p[nt][r];
            }
            #pragma unroll
            for (int off = 1; off < 16; off <<= 1)
                rs += __shfl_xor(rs, off, 64);
            l_i[r] = l_i[r] * alpha + rs;
            #pragma unroll
            for (int nt = 0; nt < 4; nt++) accO[nt][r] *= alpha;
        }

        // P -> per-wave LDS rows [wq*16, +16), layout [m][t_k] stride 72
        #pragma unroll
        for (int nt = 0; nt < 4; nt++)
            #pragma unroll
            for (int r = 0; r < 4; r++)
                sP[(wq * 16 + lq * 4 + r) * 72 + nt * 16 + l15] =
                    (short)f2bf(p[nt][r]);
        __asm__ volatile("s_waitcnt lgkmcnt(0)" ::: "memory");

        // O += P·V  (B from V^T tile: n = d, k = t_k)
        short8 ap0 = *(short8*)(sP + (wq * 16 + l15) * 72 + lq * 8);
        short8 ap1 = *(short8*)(sP + (wq * 16 + l15) * 72 + 32 + lq * 8);
        #pragma unroll
        for (int nt = 0; nt < 4; nt++) {
            short8 b0 = *(short8*)(sV + (nt * 16 + l15) * 72 + lq * 8);
            short8 b1 = *(short8*)(sV + (nt * 16 + l15) * 72 + 32 + lq * 8);
            accO[nt] = mfma16(ap0, b0, accO[nt]);
            accO[nt] = mfma16(ap1, b1, accO[nt]);
        }
    }

    unsigned short* aB = att + ((size_t)bh * TT + qTile * 64 + wq * 16 + lq * 4) * DD;
    #pragma unroll
    for (int r = 0; r < 4; r++) {
        float inv = 1.0f / l_i[r];
        #pragma unroll
        for (int nt = 0; nt < 4; nt++)
            aB[(size_t)r * DD + nt * 16 + l15] = f2bf(accO[nt][r] * inv);
    }
}

// ---------------------------------------------------------------------------
// Kernel 3: output conv1x1 (bf16 MFMA). B operand = att[b,h,t,d] which is
// k(=c)-contiguous per t.  Epilogue: bias + fp32 store.
// ---------------------------------------------------------------------------
__global__ __launch_bounds__(256) void oproj_mfma_kernel(
    const unsigned short* __restrict__ att, const float* __restrict__ Wo,
    const float* __restrict__ bo, float* __restrict__ out)
{
    __shared__ __align__(16) short smem[2 * 128 * 40];  // 20480 B
    short* sA = smem;
    short* sB = smem + 128 * 40;

    const int tid = threadIdx.x, lane = tid & 63, wave = tid >> 6;
    const int wm = wave >> 1, wn = wave & 1;
    const int l15 = lane & 15, lq = lane >> 4;
    const int tTile = blockIdx.x, oTile = blockIdx.y, b = blockIdx.z;
    const int oBase = oTile * 128, tBase = tTile * 128;

    const int ao = tid >> 1, ak = (tid & 1) * 16;
    const int bt = tid & 127, bk_ = (tid >> 7) * 16;
    const float* gA = Wo + (size_t)(oBase + ao) * CC + ak;

    f32x4 acc[4][4];
    #pragma unroll
    for (int mt = 0; mt < 4; mt++)
        #pragma unroll
        for (int nt = 0; nt < 4; nt++) acc[mt][nt] = (f32x4){0.f, 0.f, 0.f, 0.f};

    for (int c0 = 0; c0 < CC; c0 += 32) {
        float fa[16];
        #pragma unroll
        for (int i = 0; i < 4; i++) {
            float4 t4 = *(const float4*)(gA + c0 + 4 * i);
            fa[4*i+0] = t4.x; fa[4*i+1] = t4.y; fa[4*i+2] = t4.z; fa[4*i+3] = t4.w;
        }
        int c = c0 + bk_;
        const unsigned short* gB =
            att + (((size_t)b * HH + (c >> 6)) * TT + tBase + bt) * DD + (c & 63);
        short8 pb0 = *(const short8*)gB;
        short8 pb1 = *(const short8*)(gB + 8);

        __syncthreads();
        short8 pa0, pa1;
        #pragma unroll
        for (int e = 0; e < 8; e++) {
            pa0[e] = (short)f2bf(fa[e]); pa1[e] = (short)f2bf(fa[8 + e]);
        }
        *(short8*)(sA + ao * 40 + ak)      = pa0;
        *(short8*)(sA + ao * 40 + ak + 8)  = pa1;
        *(short8*)(sB + bt * 40 + bk_)     = pb0;
        *(short8*)(sB + bt * 40 + bk_ + 8) = pb1;
        __syncthreads();

        short8 af[4], bf[4];
        #pragma unroll
        for (int mt = 0; mt < 4; mt++)
            af[mt] = *(short8*)(sA + (wm * 64 + mt * 16 + l15) * 40 + lq * 8);
        #pragma unroll
        for (int nt = 0; nt < 4; nt++)
            bf[nt] = *(short8*)(sB + (wn * 64 + nt * 16 + l15) * 40 + lq * 8);
        #pragma unroll
        for (int mt = 0; mt < 4; mt++)
            #pragma unroll
            for (int nt = 0; nt < 4; nt++)
                acc[mt][nt] = mfma16(af[mt], bf[nt], acc[mt][nt]);
    }

    #pragma unroll
    for (int mt = 0; mt < 4; mt++)
        #pragma unroll
        for (int r = 0; r < 4; r++) {
            int o = oBase + wm * 64 + mt * 16 + lq * 4 + r;
            float bi = bo[o];
            float* dst = out + ((size_t)b * CC + o) * TT + tBase + wn * 64;
            #pragma unroll
            for (int nt = 0; nt < 4; nt++)
                dst[nt * 16 + l15] = acc[mt][nt][r] + bi;
        }
}

// ---------------------------------------------------------------------------
extern "C" void kernel_launch(void* const* d_in, const int* in_sizes, int n_in,
                              void* d_out, int out_size, void* d_ws, size_t ws_size,
                              hipStream_t stream)
{
    const float* x   = (const float*)d_in[0];
    const float* ctx = (const float*)d_in[1];
    const int* mask  = (const int*)d_in[2];
    const float* Wq  = (const float*)d_in[3];
    const float* bq  = (const float*)d_in[4];
    const float* Wk  = (const float*)d_in[5];
    const float* bk  = (const float*)d_in[6];
    const float* Wv  = (const float*)d_in[7];
    const float* bv  = (const float*)d_in[8];
    const float* Wo  = (const float*)d_in[9];
    const float* bo  = (const float*)d_in[10];
    float* out = (float*)d_out;

    const size_t nq = (size_t)BB * HH * TT * DD;  // 8M elems
    unsigned short* q   = (unsigned short*)d_ws;  // bf16, [b,h,t,d]
    unsigned short* k   = q + nq;                 // bf16, [b,h,t,d]
    unsigned short* v   = k + nq;                 // bf16, [b,h,d,t]
    unsigned short* att = v + nq;                 // bf16, [b,h,t,d]

    qkv_mfma_kernel<<<dim3(8, 8, BB * 3), 256, 0, stream>>>(
        x, ctx, Wq, bq, Wk, bk, Wv, bv, q, k, v);
    attn_mfma_kernel<<<dim3(TT / 64, BB * HH), 256, 0, stream>>>(q, k, v, mask, att);
    oproj_mfma_kernel<<<dim3(8, 8, BB), 256, 0, stream>>>(att, Wo, bo, out);
}

// Round 3
// 435.867 us; speedup vs baseline: 4.4896x; 1.7170x over previous
//
#include <hip/hip_runtime.h>
#include <hip/hip_bf16.h>
#include <math.h>

#define BB 8
#define CC 1024
#define TT 1024
#define HH 16
#define DD 64

typedef __attribute__((ext_vector_type(8))) short short8;
typedef __attribute__((ext_vector_type(4))) short short4_;
typedef __attribute__((ext_vector_type(4))) float f32x4;

__device__ __forceinline__ unsigned short f2bf(float f) {
    unsigned u = __builtin_bit_cast(unsigned, f);
    u += 0x7fffu + ((u >> 16) & 1u);
    return (unsigned short)(u >> 16);
}

__device__ __forceinline__ f32x4 mfma16(short8 a, short8 b, f32x4 c) {
    return __builtin_amdgcn_mfma_f32_16x16x32_bf16(a, b, c, 0, 0, 0);
}

// DPP cross-lane move within rows of 16 (VALU-rate, no LDS)
template<int CTRL>
__device__ __forceinline__ float dpp_mv(float x) {
    return __builtin_bit_cast(float,
        __builtin_amdgcn_update_dpp(0, __builtin_bit_cast(int, x),
                                    CTRL, 0xF, 0xF, false));
}
// valid order: xor1 (quad_perm 1032), xor2 (quad_perm 2301), then the
// mirrors (which equal xor4/xor8 only once values are quad/8-uniform).
__device__ __forceinline__ float rowmax16(float x) {
    x = fmaxf(x, dpp_mv<0xB1>(x));
    x = fmaxf(x, dpp_mv<0x4E>(x));
    x = fmaxf(x, dpp_mv<0x141>(x));
    x = fmaxf(x, dpp_mv<0x140>(x));
    return x;
}
__device__ __forceinline__ float rowsum16(float x) {
    x += dpp_mv<0xB1>(x);
    x += dpp_mv<0x4E>(x);
    x += dpp_mv<0x141>(x);
    x += dpp_mv<0x140>(x);
    return x;
}

// ---------------------------------------------------------------------------
// Kernel 1: QKV conv1x1 (bf16 MFMA) + bias + RoPE + head-split.
// ---------------------------------------------------------------------------
__global__ __launch_bounds__(256) void qkv_mfma_kernel(
    const float* __restrict__ x, const float* __restrict__ ctx,
    const float* __restrict__ Wq, const float* __restrict__ bq,
    const float* __restrict__ Wk, const float* __restrict__ bk,
    const float* __restrict__ Wv, const float* __restrict__ bv,
    unsigned short* __restrict__ qo, unsigned short* __restrict__ ko,
    unsigned short* __restrict__ vo)
{
    __shared__ __align__(16) short smem[4 * 64 * 72];  // 36864 B
    short* sA = smem;              // W tile   [o 128][c 32] stride 40
    short* sB = smem + 128 * 40;   // In^T tile[t 128][c 32] stride 40

    const int tid  = threadIdx.x;
    const int lane = tid & 63;
    const int wave = tid >> 6;
    const int wm = wave >> 1, wn = wave & 1;
    const int l15 = lane & 15, lq = lane >> 4;

    const int tTile = blockIdx.x, oTile = blockIdx.y;
    const int b = blockIdx.z / 3, w = blockIdx.z % 3;
    const int oBase = oTile * 128, tBase = tTile * 128;

    const float* In   = (w == 0) ? x  : ctx;
    const float* W    = (w == 0) ? Wq : (w == 1) ? Wk : Wv;
    const float* bias = (w == 0) ? bq : (w == 1) ? bk : bv;
    const float* InB  = In + (size_t)b * CC * TT;

    const int ao = tid >> 1, ak = (tid & 1) * 16;       // A staging role
    const int bt = tid & 127, bk_ = (tid >> 7) * 16;    // B staging role
    const float* gA = W + (size_t)(oBase + ao) * CC + ak;
    const float* gB = InB + (size_t)bk_ * TT + tBase + bt;

    f32x4 acc[4][4];
    #pragma unroll
    for (int mt = 0; mt < 4; mt++)
        #pragma unroll
        for (int nt = 0; nt < 4; nt++) acc[mt][nt] = (f32x4){0.f, 0.f, 0.f, 0.f};

    for (int c0 = 0; c0 < CC; c0 += 32) {
        float fa[16], fb[16];
        #pragma unroll
        for (int i = 0; i < 4; i++) {
            float4 t4 = *(const float4*)(gA + c0 + 4 * i);
            fa[4*i+0] = t4.x; fa[4*i+1] = t4.y; fa[4*i+2] = t4.z; fa[4*i+3] = t4.w;
        }
        #pragma unroll
        for (int j = 0; j < 16; j++)
            fb[j] = gB[(size_t)(c0 + j) * TT];

        __syncthreads();
        short8 pa0, pa1, pb0, pb1;
        #pragma unroll
        for (int e = 0; e < 8; e++) {
            pa0[e] = (short)f2bf(fa[e]);   pa1[e] = (short)f2bf(fa[8 + e]);
            pb0[e] = (short)f2bf(fb[e]);   pb1[e] = (short)f2bf(fb[8 + e]);
        }
        *(short8*)(sA + ao * 40 + ak)     = pa0;
        *(short8*)(sA + ao * 40 + ak + 8) = pa1;
        *(short8*)(sB + bt * 40 + bk_)     = pb0;
        *(short8*)(sB + bt * 40 + bk_ + 8) = pb1;
        __syncthreads();

        short8 af[4], bf[4];
        #pragma unroll
        for (int mt = 0; mt < 4; mt++)
            af[mt] = *(short8*)(sA + (wm * 64 + mt * 16 + l15) * 40 + lq * 8);
        #pragma unroll
        for (int nt = 0; nt < 4; nt++)
            bf[nt] = *(short8*)(sB + (wn * 64 + nt * 16 + l15) * 40 + lq * 8);
        #pragma unroll
        for (int mt = 0; mt < 4; mt++)
            #pragma unroll
            for (int nt = 0; nt < 4; nt++)
                acc[mt][nt] = mfma16(af[mt], bf[nt], acc[mt][nt]);
    }

    // bias (C-layout: row o = mt*16 + lq*4 + r, col t = nt*16 + l15)
    #pragma unroll
    for (int mt = 0; mt < 4; mt++)
        #pragma unroll
        for (int r = 0; r < 4; r++) {
            float bi = bias[oBase + wm * 64 + mt * 16 + lq * 4 + r];
            #pragma unroll
            for (int nt = 0; nt < 4; nt++) acc[mt][nt][r] += bi;
        }

    const int h = oTile * 2 + wm;
    __syncthreads();  // everyone done with sA/sB before transpose reuse
    short* sT = smem + wave * (64 * 72);

    if (w < 2) {
        // RoPE: d = mt*16 + lq*4 + r; pair (d, d+16) = (mt=0, mt=1), d<16
        #pragma unroll
        for (int r = 0; r < 4; r++) {
            float theta = powf(10000.0f, -(float)(lq * 4 + r) * (1.0f / 16.0f));
            #pragma unroll
            for (int nt = 0; nt < 4; nt++) {
                float tpos = (float)(tBase + wn * 64 + nt * 16 + l15);
                float sa, ca;
                sincosf(tpos * theta, &sa, &ca);
                float x0 = acc[0][nt][r], x1 = acc[1][nt][r];
                acc[0][nt][r] = x0 * ca - x1 * sa;
                acc[1][nt][r] = x1 * ca + x0 * sa;
            }
        }
        // transpose to [t_local][d] (stride 72)
        #pragma unroll
        for (int nt = 0; nt < 4; nt++)
            #pragma unroll
            for (int mt = 0; mt < 4; mt++) {
                short4_ v4;
                #pragma unroll
                for (int r = 0; r < 4; r++) v4[r] = (short)f2bf(acc[mt][nt][r]);
                *(short4_*)(sT + (nt * 16 + l15) * 72 + mt * 16 + lq * 4) = v4;
            }
    } else {
        // V: buffer as [d][t_local] (stride 72), no RoPE
        #pragma unroll
        for (int mt = 0; mt < 4; mt++)
            #pragma unroll
            for (int r = 0; r < 4; r++)
                #pragma unroll
                for (int nt = 0; nt < 4; nt++)
                    sT[(mt * 16 + lq * 4 + r) * 72 + nt * 16 + l15] =
                        (short)f2bf(acc[mt][nt][r]);
    }
    __asm__ volatile("s_waitcnt lgkmcnt(0)" ::: "memory");  // within-wave LDS order

    unsigned short* dstBase;
    if (w == 0)
        dstBase = qo + ((size_t)(b * HH + h) * TT + tBase + wn * 64 + lane) * DD;
    else if (w == 1)
        dstBase = ko + ((size_t)(b * HH + h) * TT + tBase + wn * 64 + lane) * DD;
    else
        dstBase = vo + ((size_t)(b * HH + h) * DD + lane) * TT + tBase + wn * 64;
    #pragma unroll
    for (int j = 0; j < 8; j++)
        *(short8*)(dstBase + j * 8) = *(short8*)(sT + lane * 72 + j * 8);
}

// ---------------------------------------------------------------------------
// Kernel 2: flash attention, bf16 MFMA, base-2 online softmax, DPP reductions.
// Block = 4 waves, Q-tile 64 rows, wave owns 16 q-rows. K-tile 64.
// ---------------------------------------------------------------------------
__global__ __launch_bounds__(256) void attn_mfma_kernel(
    const unsigned short* __restrict__ q, const unsigned short* __restrict__ k,
    const unsigned short* __restrict__ v, const int* __restrict__ mask,
    unsigned short* __restrict__ att)
{
    __shared__ __align__(16) short sQ[64 * 72];
    __shared__ __align__(16) short sK[64 * 72];
    __shared__ __align__(16) short sV[64 * 72];  // V^T tile: [d][t_k]
    __shared__ __align__(16) short sP[64 * 72];

    const int tid = threadIdx.x, lane = tid & 63, wq = tid >> 6;
    const int l15 = lane & 15, lq = lane >> 4;
    const int qTile = blockIdx.x, bh = blockIdx.y, b = bh >> 4;

    const int sr = tid >> 2, sc = (tid & 3) * 16;  // staging: row, col-chunk

    const float SCALE   = 0.125f * 1.44269504f;   // 1/sqrt(64) * log2(e)
    const float NEGINF2 = -14426.95f;             // -10000 * log2(e)

    {   // stage Q once
        const unsigned short* gq = q + ((size_t)bh * TT + qTile * 64 + sr) * DD + sc;
        *(short8*)(sQ + sr * 72 + sc)     = *(const short8*)gq;
        *(short8*)(sQ + sr * 72 + sc + 8) = *(const short8*)(gq + 8);
    }
    __syncthreads();

    // Q fragments are loop-invariant: hoist out of the K-loop
    const short8 aq0 = *(short8*)(sQ + (wq * 16 + l15) * 72 + lq * 8);
    const short8 aq1 = *(short8*)(sQ + (wq * 16 + l15) * 72 + 32 + lq * 8);

    f32x4 accO[4];
    float m_i[4], l_i[4];
    #pragma unroll
    for (int r = 0; r < 4; r++) {
        m_i[r] = -1e30f; l_i[r] = 0.f;
        accO[r] = (f32x4){0.f, 0.f, 0.f, 0.f};
    }

    const int qpos0 = qTile * 64 + wq * 16 + lq * 4;
    const int* maskB = mask + b * TT;
    const unsigned short* kB = k + (size_t)bh * TT * DD;
    const unsigned short* vB = v + (size_t)bh * DD * TT;

    for (int kt = 0; kt < 16; kt++) {
        const unsigned short* gk = kB + (size_t)(kt * 64 + sr) * DD + sc;
        short8 k0 = *(const short8*)gk;
        short8 k1 = *(const short8*)(gk + 8);
        const unsigned short* gv = vB + (size_t)sr * TT + kt * 64 + sc;
        short8 v0 = *(const short8*)gv;
        short8 v1 = *(const short8*)(gv + 8);

        __syncthreads();   // prior iteration's reads of sK/sV done
        *(short8*)(sK + sr * 72 + sc)     = k0;
        *(short8*)(sK + sr * 72 + sc + 8) = k1;
        *(short8*)(sV + sr * 72 + sc)     = v0;
        *(short8*)(sV + sr * 72 + sc + 8) = v1;
        __syncthreads();

        // S = Q·K^T
        f32x4 s4[4];
        #pragma unroll
        for (int nt = 0; nt < 4; nt++) {
            short8 b0 = *(short8*)(sK + (nt * 16 + l15) * 72 + lq * 8);
            short8 b1 = *(short8*)(sK + (nt * 16 + l15) * 72 + 32 + lq * 8);
            f32x4 z = (f32x4){0.f, 0.f, 0.f, 0.f};
            z = mfma16(aq0, b0, z);
            z = mfma16(aq1, b1, z);
            s4[nt] = z;
        }

        // base-2 domain: s2 = qk*SCALE - log2(1+|k-q|); mask -> NEGINF2
        float s[4][4];
        #pragma unroll
        for (int nt = 0; nt < 4; nt++) {
            int kpos = kt * 64 + nt * 16 + l15;
            int mk = maskB[kpos];
            float fb = (float)(kpos - qpos0);
            #pragma unroll
            for (int r = 0; r < 4; r++) {
                float bias = __log2f(1.0f + fabsf(fb - (float)r));
                float sv_ = fmaf(s4[nt][r], SCALE, -bias);
                s[nt][r] = mk ? sv_ : NEGINF2;
            }
        }

        // online softmax per row r (DPP reduction across 16 lanes)
        float p[4][4];
        #pragma unroll
        for (int r = 0; r < 4; r++) {
            float mt_ = fmaxf(fmaxf(s[0][r], s[1][r]), fmaxf(s[2][r], s[3][r]));
            mt_ = rowmax16(mt_);
            float mn = fmaxf(m_i[r], mt_);
            float alpha = exp2f(m_i[r] - mn);
            m_i[r] = mn;
            float rs = 0.f;
            #pragma unroll
            for (int nt = 0; nt < 4; nt++) {
                p[nt][r] = exp2f(s[nt][r] - mn);
                rs += p[nt][r];
            }
            rs = rowsum16(rs);
            l_i[r] = fmaf(l_i[r], alpha, rs);
            #pragma unroll
            for (int nt = 0; nt < 4; nt++) accO[nt][r] *= alpha;
        }

        // P -> per-wave LDS rows [wq*16, +16), layout [m][t_k] stride 72
        #pragma unroll
        for (int nt = 0; nt < 4; nt++)
            #pragma unroll
            for (int r = 0; r < 4; r++)
                sP[(wq * 16 + lq * 4 + r) * 72 + nt * 16 + l15] =
                    (short)f2bf(p[nt][r]);
        __asm__ volatile("s_waitcnt lgkmcnt(0)" ::: "memory");

        // O += P·V  (B from V^T tile: n = d, k = t_k)
        short8 ap0 = *(short8*)(sP + (wq * 16 + l15) * 72 + lq * 8);
        short8 ap1 = *(short8*)(sP + (wq * 16 + l15) * 72 + 32 + lq * 8);
        #pragma unroll
        for (int nt = 0; nt < 4; nt++) {
            short8 b0 = *(short8*)(sV + (nt * 16 + l15) * 72 + lq * 8);
            short8 b1 = *(short8*)(sV + (nt * 16 + l15) * 72 + 32 + lq * 8);
            accO[nt] = mfma16(ap0, b0, accO[nt]);
            accO[nt] = mfma16(ap1, b1, accO[nt]);
        }
    }

    unsigned short* aB = att + ((size_t)bh * TT + qTile * 64 + wq * 16 + lq * 4) * DD;
    #pragma unroll
    for (int r = 0; r < 4; r++) {
        float inv = 1.0f / l_i[r];
        #pragma unroll
        for (int nt = 0; nt < 4; nt++)
            aB[(size_t)r * DD + nt * 16 + l15] = f2bf(accO[nt][r] * inv);
    }
}

// ---------------------------------------------------------------------------
// Kernel 3: output conv1x1 (bf16 MFMA).
// ---------------------------------------------------------------------------
__global__ __launch_bounds__(256) void oproj_mfma_kernel(
    const unsigned short* __restrict__ att, const float* __restrict__ Wo,
    const float* __restrict__ bo, float* __restrict__ out)
{
    __shared__ __align__(16) short smem[2 * 128 * 40];  // 20480 B
    short* sA = smem;
    short* sB = smem + 128 * 40;

    const int tid = threadIdx.x, lane = tid & 63, wave = tid >> 6;
    const int wm = wave >> 1, wn = wave & 1;
    const int l15 = lane & 15, lq = lane >> 4;
    const int tTile = blockIdx.x, oTile = blockIdx.y, b = blockIdx.z;
    const int oBase = oTile * 128, tBase = tTile * 128;

    const int ao = tid >> 1, ak = (tid & 1) * 16;
    const int bt = tid & 127, bk_ = (tid >> 7) * 16;
    const float* gA = Wo + (size_t)(oBase + ao) * CC + ak;

    f32x4 acc[4][4];
    #pragma unroll
    for (int mt = 0; mt < 4; mt++)
        #pragma unroll
        for (int nt = 0; nt < 4; nt++) acc[mt][nt] = (f32x4){0.f, 0.f, 0.f, 0.f};

    for (int c0 = 0; c0 < CC; c0 += 32) {
        float fa[16];
        #pragma unroll
        for (int i = 0; i < 4; i++) {
            float4 t4 = *(const float4*)(gA + c0 + 4 * i);
            fa[4*i+0] = t4.x; fa[4*i+1] = t4.y; fa[4*i+2] = t4.z; fa[4*i+3] = t4.w;
        }
        int c = c0 + bk_;
        const unsigned short* gB =
            att + (((size_t)b * HH + (c >> 6)) * TT + tBase + bt) * DD + (c & 63);
        short8 pb0 = *(const short8*)gB;
        short8 pb1 = *(const short8*)(gB + 8);

        __syncthreads();
        short8 pa0, pa1;
        #pragma unroll
        for (int e = 0; e < 8; e++) {
            pa0[e] = (short)f2bf(fa[e]); pa1[e] = (short)f2bf(fa[8 + e]);
        }
        *(short8*)(sA + ao * 40 + ak)      = pa0;
        *(short8*)(sA + ao * 40 + ak + 8)  = pa1;
        *(short8*)(sB + bt * 40 + bk_)     = pb0;
        *(short8*)(sB + bt * 40 + bk_ + 8) = pb1;
        __syncthreads();

        short8 af[4], bf[4];
        #pragma unroll
        for (int mt = 0; mt < 4; mt++)
            af[mt] = *(short8*)(sA + (wm * 64 + mt * 16 + l15) * 40 + lq * 8);
        #pragma unroll
        for (int nt = 0; nt < 4; nt++)
            bf[nt] = *(short8*)(sB + (wn * 64 + nt * 16 + l15) * 40 + lq * 8);
        #pragma unroll
        for (int mt = 0; mt < 4; mt++)
            #pragma unroll
            for (int nt = 0; nt < 4; nt++)
                acc[mt][nt] = mfma16(af[mt], bf[nt], acc[mt][nt]);
    }

    #pragma unroll
    for (int mt = 0; mt < 4; mt++)
        #pragma unroll
        for (int r = 0; r < 4; r++) {
            int o = oBase + wm * 64 + mt * 16 + lq * 4 + r;
            float bi = bo[o];
            float* dst = out + ((size_t)b * CC + o) * TT + tBase + wn * 64;
            #pragma unroll
            for (int nt = 0; nt < 4; nt++)
                dst[nt * 16 + l15] = acc[mt][nt][r] + bi;
        }
}

// ---------------------------------------------------------------------------
extern "C" void kernel_launch(void* const* d_in, const int* in_sizes, int n_in,
                              void* d_out, int out_size, void* d_ws, size_t ws_size,
                              hipStream_t stream)
{
    const float* x   = (const float*)d_in[0];
    const float* ctx = (const float*)d_in[1];
    const int* mask  = (const int*)d_in[2];
    const float* Wq  = (const float*)d_in[3];
    const float* bq  = (const float*)d_in[4];
    const float* Wk  = (const float*)d_in[5];
    const float* bk  = (const float*)d_in[6];
    const float* Wv  = (const float*)d_in[7];
    const float* bv  = (const float*)d_in[8];
    const float* Wo  = (const float*)d_in[9];
    const float* bo  = (const float*)d_in[10];
    float* out = (float*)d_out;

    const size_t nq = (size_t)BB * HH * TT * DD;  // 8M elems
    unsigned short* q   = (unsigned short*)d_ws;  // bf16, [b,h,t,d]
    unsigned short* k   = q + nq;                 // bf16, [b,h,t,d]
    unsigned short* v   = k + nq;                 // bf16, [b,h,d,t]
    unsigned short* att = v + nq;                 // bf16, [b,h,t,d]

    qkv_mfma_kernel<<<dim3(8, 8, BB * 3), 256, 0, stream>>>(
        x, ctx, Wq, bq, Wk, bk, Wv, bv, q, k, v);
    attn_mfma_kernel<<<dim3(TT / 64, BB * HH), 256, 0, stream>>>(q, k, v, mask, att);
    oproj_mfma_kernel<<<dim3(8, 8, BB), 256, 0, stream>>>(att, Wo, bo, out);
}